// Round 2
// baseline (19.808 us; speedup 1.0000x reference)
//
#include <hip/hip_runtime.h>

// Problem constants (B=1024, I=128, H=512, O=16)
#define B_DIM 1024
#define I_DIM 128
#define H_DIM 512
#define O_CNT 16

// Full 64-lane butterfly reduction (wave = 64 on CDNA4).
__device__ __forceinline__ float wave_reduce_sum(float v) {
#pragma unroll
    for (int off = 32; off > 0; off >>= 1)
        v += __shfl_xor(v, off, 64);
    return v;
}

// Kernel A: u[o*H + h] = sum_k W2[o, h, k] * W3[o, k]
// One wave per (o, h) row: 512 floats = 128 float4; lane reads f4[lane], f4[lane+64].
// HBM-bound (16 MB of W2) -> full-chip grid.
__global__ __launch_bounds__(256) void k_w2w3(const float* __restrict__ W2,
                                              const float* __restrict__ W3,
                                              float* __restrict__ u) {
    const int wid  = (blockIdx.x * 256 + threadIdx.x) >> 6;  // [0, 8192)
    const int lane = threadIdx.x & 63;
    const int o = wid >> 9;      // / 512
    const float4* row = (const float4*)(W2 + (size_t)wid * H_DIM);
    const float4* w3  = (const float4*)(W3 + (size_t)o * H_DIM);
    float4 a0 = row[lane];
    float4 a1 = row[lane + 64];
    float4 b0 = w3[lane];
    float4 b1 = w3[lane + 64];
    float acc = a0.x * b0.x + a0.y * b0.y + a0.z * b0.z + a0.w * b0.w
              + a1.x * b1.x + a1.y * b1.y + a1.z * b1.z + a1.w * b1.w;
    acc = wave_reduce_sum(acc);
    if (lane == 0) u[wid] = acc;
}

// Kernel B (fused): one block per option o.
//   Phase A: v[i] = sum_h W1[o,i,h] * u[o,h]   (16 waves x 8 rows), v -> LDS
//   Phase B: for each sample b with option[b]==o: out[b] = dot(state[b], v)
// Each out[b] has exactly one writer block -> no atomics, no memset.
__global__ __launch_bounds__(1024) void k_fused_vout(const float* __restrict__ W1,
                                                     const float* __restrict__ u,
                                                     const float* __restrict__ state,
                                                     const int* __restrict__ option,
                                                     float* __restrict__ out) {
    const int o    = blockIdx.x;         // [0, 16)
    const int tid  = threadIdx.x;        // [0, 1024)
    const int w    = tid >> 6;           // wave [0, 16)
    const int lane = tid & 63;

    __shared__ float v_s[I_DIM];         // 128 floats
    __shared__ int   opt_s[B_DIM];       // 1024 ints

    // Stage option[] (one load per thread, overlapped with phase A loads).
    opt_s[tid] = option[tid];

    // u fragment: loaded once per lane, reused across this wave's 8 rows.
    const float4* uo = (const float4*)(u + (size_t)o * H_DIM);
    float4 b0 = uo[lane];
    float4 b1 = uo[lane + 64];

#pragma unroll
    for (int r = 0; r < 8; ++r) {
        const int i = w * 8 + r;
        const float4* row = (const float4*)(W1 + ((size_t)o * I_DIM + i) * H_DIM);
        float4 a0 = row[lane];
        float4 a1 = row[lane + 64];
        float acc = a0.x * b0.x + a0.y * b0.y + a0.z * b0.z + a0.w * b0.w
                  + a1.x * b1.x + a1.y * b1.y + a1.z * b1.z + a1.w * b1.w;
        acc = wave_reduce_sum(acc);
        if (lane == 0) v_s[i] = acc;
    }
    __syncthreads();

    // Phase B: wave w owns samples b = w, w+16, w+32, ... (64 candidates, ~4 hits).
    const float2 vv = *(const float2*)(v_s + 2 * lane);   // 2-way LDS access = conflict-free
    for (int t = 0; t < B_DIM / 16; ++t) {
        const int b = w + (t << 4);
        if (opt_s[b] == o) {
            const float2* srow = (const float2*)(state + (size_t)b * I_DIM);
            float2 s = srow[lane];
            float acc = s.x * vv.x + s.y * vv.y;
            acc = wave_reduce_sum(acc);
            if (lane == 0) out[b] = acc;
        }
    }
}

extern "C" void kernel_launch(void* const* d_in, const int* in_sizes, int n_in,
                              void* d_out, int out_size, void* d_ws, size_t ws_size,
                              hipStream_t stream) {
    const float* state  = (const float*)d_in[0];
    // d_in[1] = action, unused by the reference forward.
    const float* W1     = (const float*)d_in[2];
    const float* W2     = (const float*)d_in[3];
    const float* W3     = (const float*)d_in[4];
    const int*   option = (const int*)d_in[5];
    float* out = (float*)d_out;

    float* u = (float*)d_ws;   // 16*512 floats = 32 KiB scratch

    // K1: 16*512 = 8192 waves -> 2048 blocks of 256 threads (full chip, HBM-bound).
    k_w2w3<<<2048, 256, 0, stream>>>(W2, W3, u);
    // K2: one block per option, 1024 threads (16 waves).
    k_fused_vout<<<O_CNT, 1024, 0, stream>>>(W1, u, state, option, out);
}